// Round 1
// baseline (1475.991 us; speedup 1.0000x reference)
//
#include <hip/hip_runtime.h>
#include <hip/hip_bf16.h>
#include <stdint.h>

// ---------------------------------------------------------------------------
// BoardEmbeddingWithTopology: embed GEMM -> QKV GEMM -> per-head attention
// with learned 64x64 relative bias -> O-proj GEMM + residual -> LayerNorm.
// All GEMMs: bf16 MFMA 16x16x32, 128x128 tile, BK=32, global_load_lds(16B),
// 4 waves x (4x4 16x16 frags). Weights pre-transposed to (N,K) bf16 so both
// A and B fragments are 16B-contiguous LDS reads (m97 "gemm_bt" pattern).
// ---------------------------------------------------------------------------

typedef float  floatx4 __attribute__((ext_vector_type(4)));
typedef short  bf16x8  __attribute__((ext_vector_type(8)));
typedef short  bf16x4  __attribute__((ext_vector_type(4)));

__device__ __forceinline__ short f2bf(float f) {
  __hip_bfloat16 h = __float2bfloat16(f);
  return *reinterpret_cast<short*>(&h);
}
__device__ __forceinline__ float bf2f(short s) {
  union { float f; uint32_t u; } c;
  c.u = ((uint32_t)(uint16_t)s) << 16;
  return c.f;
}
__device__ __forceinline__ floatx4 mfma16(bf16x8 a, bf16x8 b, floatx4 c) {
  return __builtin_amdgcn_mfma_f32_16x16x32_bf16(a, b, c, 0, 0, 0);
}

// async global->LDS, 16B per lane; lds dst must be wave-uniform base.
#define ASYNC_CP16(gsrc, ldst)                                                 \
  __builtin_amdgcn_global_load_lds(                                            \
      (const __attribute__((address_space(1))) void*)(gsrc),                   \
      (__attribute__((address_space(3))) void*)(ldst), 16, 0, 0)

// ---------------------------------------------------------------------------
// Prep: transpose 1024x1024 f32 weight -> (N,K) bf16
// ---------------------------------------------------------------------------
__global__ void k_transpose_bf16(const float* __restrict__ src,
                                 short* __restrict__ dst) {
  __shared__ float tile[32][33];
  const int bx = blockIdx.x * 32, by = blockIdx.y * 32;
  const int tx = threadIdx.x, ty = threadIdx.y;
#pragma unroll
  for (int i = 0; i < 32; i += 8)
    tile[ty + i][tx] = src[(size_t)(by + ty + i) * 1024 + bx + tx];
  __syncthreads();
#pragma unroll
  for (int i = 0; i < 32; i += 8)
    dst[(size_t)(bx + ty + i) * 1024 + by + tx] = f2bf(tile[tx][ty + i]);
}

// embW (119,1024) f32 -> embW_t (1024,128) bf16, zero-padded K 119->128
__global__ void k_embWt(const float* __restrict__ embW, short* __restrict__ dst) {
  const int idx = blockIdx.x * 256 + threadIdx.x;  // 1024*128
  const int n = idx >> 7, c = idx & 127;
  dst[idx] = f2bf((c < 119) ? embW[(size_t)c * 1024 + n] : 0.f);
}

// ---------------------------------------------------------------------------
// Embed: x[b,s,n] = sum_c board[b,c,s]*embW[c,n] + emb_b[n] + pos[s,n] (bf16)
// one block per (board b, 128-col ntile); A = board[b]^T staged in LDS.
// ---------------------------------------------------------------------------
__global__ __launch_bounds__(256) void k_embed(
    const float* __restrict__ board, const short* __restrict__ embWt,
    const float* __restrict__ emb_b, const float* __restrict__ pos,
    short* __restrict__ x) {
  __shared__ short As[64 * 136];   // [s][c], +8 pad breaks write conflicts
  __shared__ short Bs[128 * 32];   // [n][k-chunk]
  const int t = threadIdx.x, l = t & 63, w = t >> 6;
  const int quad = l >> 4, lan = l & 15;
  const int b = blockIdx.x >> 3, nBase = (blockIdx.x & 7) << 7;
  const float* bb = board + (size_t)b * (119 * 64);
  const int s = t & 63;
#pragma unroll
  for (int it = 0; it < 16; ++it) {
    const int c0 = ((t >> 6) + it * 4) * 2;
    float u0 = (c0 < 119) ? bb[c0 * 64 + s] : 0.f;
    float u1 = (c0 + 1 < 119) ? bb[(c0 + 1) * 64 + s] : 0.f;
    short2 pr; pr.x = f2bf(u0); pr.y = f2bf(u1);
    *(short2*)&As[s * 136 + c0] = pr;
  }
  const short* Bg0 = embWt + (size_t)(nBase + (t >> 2)) * 128 + (t & 3) * 8;
  const short* Bg1 = Bg0 + (size_t)64 * 128;
  short* Bs0 = &Bs[(w * 16) * 32];
  short* Bs1 = &Bs[(64 + w * 16) * 32];
  floatx4 acc[4][2] = {};
  __syncthreads();
  for (int kk = 0; kk < 4; ++kk) {
    ASYNC_CP16(Bg0 + kk * 32, Bs0);
    ASYNC_CP16(Bg1 + kk * 32, Bs1);
    __syncthreads();
    bf16x8 af[4], bfr[2];
#pragma unroll
    for (int mt = 0; mt < 4; ++mt)
      af[mt] = *(const bf16x8*)&As[(mt * 16 + lan) * 136 + kk * 32 + quad * 8];
#pragma unroll
    for (int n2 = 0; n2 < 2; ++n2)
      bfr[n2] = *(const bf16x8*)&Bs[(w * 32 + n2 * 16 + lan) * 32 + quad * 8];
#pragma unroll
    for (int mt = 0; mt < 4; ++mt)
#pragma unroll
      for (int n2 = 0; n2 < 2; ++n2)
        acc[mt][n2] = mfma16(af[mt], bfr[n2], acc[mt][n2]);
    __syncthreads();
  }
#pragma unroll
  for (int n2 = 0; n2 < 2; ++n2) {
    const int n = nBase + w * 32 + n2 * 16 + lan;
    const float bi = emb_b[n];
#pragma unroll
    for (int mt = 0; mt < 4; ++mt) {
      const int s0 = mt * 16 + quad * 4;
      floatx4 v = acc[mt][n2];
#pragma unroll
      for (int r = 0; r < 4; ++r) {
        const int ss = s0 + r;
        x[((size_t)b * 64 + ss) * 1024 + n] = f2bf(v[r] + bi + pos[ss * 1024 + n]);
      }
    }
  }
}

// ---------------------------------------------------------------------------
// QKV GEMM: x(65536,1024)bf16 @ Wqkv_t(3072,1024)bf16 -> q,k (b,h,s,dh) and
// v transposed (b,h,dh,s), all bf16. m97 structure.
// ---------------------------------------------------------------------------
__global__ __launch_bounds__(256) void k_gemm_qkv(
    const short* __restrict__ A, const short* __restrict__ Bt,
    const float* __restrict__ bq, const float* __restrict__ bk,
    const float* __restrict__ bv, short* __restrict__ qb,
    short* __restrict__ kb, short* __restrict__ vtb) {
  __shared__ short As[128 * 32];
  __shared__ short Bs[128 * 32];
  const int t = threadIdx.x, l = t & 63, w = t >> 6;
  const int quad = l >> 4, lan = l & 15;
  const int mBase = (blockIdx.x & 511) << 7;
  const int nBase = (blockIdx.x >> 9) << 7;
  const int wm = w >> 1, wn = w & 1;

  const short* Ag0 = A + (size_t)(mBase + (t >> 2)) * 1024 + (t & 3) * 8;
  const short* Ag1 = Ag0 + (size_t)64 * 1024;
  const short* Bg0 = Bt + (size_t)(nBase + (t >> 2)) * 1024 + (t & 3) * 8;
  const short* Bg1 = Bg0 + (size_t)64 * 1024;
  short* As0 = &As[(w * 16) * 32];
  short* As1 = &As[(64 + w * 16) * 32];
  short* Bs0 = &Bs[(w * 16) * 32];
  short* Bs1 = &Bs[(64 + w * 16) * 32];

  floatx4 acc[4][4] = {};
  for (int kk = 0; kk < 32; ++kk) {
    const int ko = kk * 32;
    ASYNC_CP16(Ag0 + ko, As0);
    ASYNC_CP16(Ag1 + ko, As1);
    ASYNC_CP16(Bg0 + ko, Bs0);
    ASYNC_CP16(Bg1 + ko, Bs1);
    __syncthreads();
    bf16x8 af[4], bfr[4];
#pragma unroll
    for (int mt = 0; mt < 4; ++mt)
      af[mt] = *(const bf16x8*)&As[(wm * 64 + mt * 16 + lan) * 32 + quad * 8];
#pragma unroll
    for (int nt = 0; nt < 4; ++nt)
      bfr[nt] = *(const bf16x8*)&Bs[(wn * 64 + nt * 16 + lan) * 32 + quad * 8];
#pragma unroll
    for (int mt = 0; mt < 4; ++mt)
#pragma unroll
      for (int nt = 0; nt < 4; ++nt)
        acc[mt][nt] = mfma16(af[mt], bfr[nt], acc[mt][nt]);
    __syncthreads();
  }
  // epilogue: block's 128 cols lie entirely in one of q/k/v (1024 % 128 == 0)
  const int region = nBase >> 10;
  const int nb = nBase & 1023;
  const float* bias = (region == 0) ? bq : (region == 1) ? bk : bv;
  short* qk = (region == 0) ? qb : kb;
#pragma unroll
  for (int nt = 0; nt < 4; ++nt) {
    const int nn = nb + wn * 64 + nt * 16 + lan;
    const int h = nn >> 6, dh = nn & 63;
    const float bi = bias[nn];
#pragma unroll
    for (int mt = 0; mt < 4; ++mt) {
      const int m0 = mBase + wm * 64 + mt * 16 + quad * 4;
      const int b = m0 >> 6, s0 = m0 & 63;
      floatx4 v = acc[mt][nt];
      if (region < 2) {
        short* dst = qk + (((size_t)b * 16 + h) * 64 + s0) * 64 + dh;
        dst[0]   = f2bf(v.x + bi);
        dst[64]  = f2bf(v.y + bi);
        dst[128] = f2bf(v.z + bi);
        dst[192] = f2bf(v.w + bi);
      } else {  // v stored transposed: vt[b,h,dh,s] -> contiguous in s
        bf16x4 pk = {f2bf(v.x + bi), f2bf(v.y + bi), f2bf(v.z + bi), f2bf(v.w + bi)};
        *(bf16x4*)(vtb + (((size_t)b * 16 + h) * 64 + dh) * 64 + s0) = pk;
      }
    }
  }
}

// ---------------------------------------------------------------------------
// Attention: one wave per (b,h). S = K @ Q^T so M=k-idx, N=q-idx: softmax
// over k is in-lane (16 regs) + shfl_xor(16,32). P -> LDS (bf16, padded
// rows) -> B-operand frags; o^T = V^T @ P via MFMA; /sum folded at store.
// ---------------------------------------------------------------------------
__global__ __launch_bounds__(256) void k_attn(
    const short* __restrict__ qb, const short* __restrict__ kb,
    const short* __restrict__ vtb, const float* __restrict__ rel_bias,
    short* __restrict__ ob) {
  __shared__ short P[4][64 * 72];  // per-wave, row stride 72 (16B-aligned, low conflict)
  const int t = threadIdx.x, l = t & 63, w = t >> 6;
  const int quad = l >> 4, lan = l & 15;
  const int b = blockIdx.x >> 2;
  const int h = (blockIdx.x & 3) * 4 + w;
  const short* q  = qb  + ((size_t)b * 16 + h) * 4096;
  const short* kp = kb  + ((size_t)b * 16 + h) * 4096;
  const short* vt = vtb + ((size_t)b * 16 + h) * 4096;
  const float* bias = rel_bias + (size_t)h * 4096;
  short* Pw = &P[w][0];

  bf16x8 kf[4][2], qf[4][2];
#pragma unroll
  for (int mt = 0; mt < 4; ++mt) {
    kf[mt][0] = *(const bf16x8*)&kp[(mt * 16 + lan) * 64 + quad * 8];
    kf[mt][1] = *(const bf16x8*)&kp[(mt * 16 + lan) * 64 + 32 + quad * 8];
  }
#pragma unroll
  for (int nt = 0; nt < 4; ++nt) {
    qf[nt][0] = *(const bf16x8*)&q[(nt * 16 + lan) * 64 + quad * 8];
    qf[nt][1] = *(const bf16x8*)&q[(nt * 16 + lan) * 64 + 32 + quad * 8];
  }
  floatx4 S[4][4];
#pragma unroll
  for (int mt = 0; mt < 4; ++mt)
#pragma unroll
    for (int nt = 0; nt < 4; ++nt) {
      floatx4 z = {0.f, 0.f, 0.f, 0.f};
      z = mfma16(kf[mt][0], qf[nt][0], z);
      S[mt][nt] = mfma16(kf[mt][1], qf[nt][1], z);
    }
  float rs[4];
#pragma unroll
  for (int nt = 0; nt < 4; ++nt) {
    const int qi = nt * 16 + lan;
    float sv[4][4];
    float m = -1e30f;
#pragma unroll
    for (int mt = 0; mt < 4; ++mt) {
      floatx4 bi = *(const floatx4*)&bias[qi * 64 + mt * 16 + quad * 4];
#pragma unroll
      for (int r = 0; r < 4; ++r) {
        sv[mt][r] = fmaf(S[mt][nt][r], 0.125f, bi[r]);
        m = fmaxf(m, sv[mt][r]);
      }
    }
    m = fmaxf(m, __shfl_xor(m, 16));
    m = fmaxf(m, __shfl_xor(m, 32));
    float sum = 0.f;
#pragma unroll
    for (int mt = 0; mt < 4; ++mt) {
      float p0 = exp2f((sv[mt][0] - m) * 1.4426950408889634f);
      float p1 = exp2f((sv[mt][1] - m) * 1.4426950408889634f);
      float p2 = exp2f((sv[mt][2] - m) * 1.4426950408889634f);
      float p3 = exp2f((sv[mt][3] - m) * 1.4426950408889634f);
      sum += p0 + p1 + p2 + p3;
      bf16x4 pk = {f2bf(p0), f2bf(p1), f2bf(p2), f2bf(p3)};
      *(bf16x4*)&Pw[qi * 72 + mt * 16 + quad * 4] = pk;
    }
    sum += __shfl_xor(sum, 16);
    sum += __shfl_xor(sum, 32);
    rs[nt] = 1.0f / sum;
  }
  bf16x8 pf[4][2];
#pragma unroll
  for (int nt = 0; nt < 4; ++nt) {
    pf[nt][0] = *(const bf16x8*)&Pw[(nt * 16 + lan) * 72 + quad * 8];
    pf[nt][1] = *(const bf16x8*)&Pw[(nt * 16 + lan) * 72 + 32 + quad * 8];
  }
#pragma unroll
  for (int mo = 0; mo < 4; ++mo) {
    bf16x8 vf0 = *(const bf16x8*)&vt[(mo * 16 + lan) * 64 + quad * 8];
    bf16x8 vf1 = *(const bf16x8*)&vt[(mo * 16 + lan) * 64 + 32 + quad * 8];
#pragma unroll
    for (int nt = 0; nt < 4; ++nt) {
      floatx4 z = {0.f, 0.f, 0.f, 0.f};
      z = mfma16(vf0, pf[nt][0], z);
      z = mfma16(vf1, pf[nt][1], z);
      const int qi = nt * 16 + lan;
      const int dh0 = mo * 16 + quad * 4;
      const float r = rs[nt];
      bf16x4 pk = {f2bf(z.x * r), f2bf(z.y * r), f2bf(z.z * r), f2bf(z.w * r)};
      *(bf16x4*)&ob[((size_t)b * 64 + qi) * 1024 + h * 64 + dh0] = pk;
    }
  }
}

// ---------------------------------------------------------------------------
// O-proj GEMM + residual: y = o @ Wo + bo + x (bf16 out)
// ---------------------------------------------------------------------------
__global__ __launch_bounds__(256) void k_gemm_oproj(
    const short* __restrict__ A, const short* __restrict__ Bt,
    const float* __restrict__ bo, const short* __restrict__ xres,
    short* __restrict__ y) {
  __shared__ short As[128 * 32];
  __shared__ short Bs[128 * 32];
  const int t = threadIdx.x, l = t & 63, w = t >> 6;
  const int quad = l >> 4, lan = l & 15;
  const int mBase = (blockIdx.x & 511) << 7;
  const int nBase = (blockIdx.x >> 9) << 7;
  const int wm = w >> 1, wn = w & 1;

  const short* Ag0 = A + (size_t)(mBase + (t >> 2)) * 1024 + (t & 3) * 8;
  const short* Ag1 = Ag0 + (size_t)64 * 1024;
  const short* Bg0 = Bt + (size_t)(nBase + (t >> 2)) * 1024 + (t & 3) * 8;
  const short* Bg1 = Bg0 + (size_t)64 * 1024;
  short* As0 = &As[(w * 16) * 32];
  short* As1 = &As[(64 + w * 16) * 32];
  short* Bs0 = &Bs[(w * 16) * 32];
  short* Bs1 = &Bs[(64 + w * 16) * 32];

  floatx4 acc[4][4] = {};
  for (int kk = 0; kk < 32; ++kk) {
    const int ko = kk * 32;
    ASYNC_CP16(Ag0 + ko, As0);
    ASYNC_CP16(Ag1 + ko, As1);
    ASYNC_CP16(Bg0 + ko, Bs0);
    ASYNC_CP16(Bg1 + ko, Bs1);
    __syncthreads();
    bf16x8 af[4], bfr[4];
#pragma unroll
    for (int mt = 0; mt < 4; ++mt)
      af[mt] = *(const bf16x8*)&As[(wm * 64 + mt * 16 + lan) * 32 + quad * 8];
#pragma unroll
    for (int nt = 0; nt < 4; ++nt)
      bfr[nt] = *(const bf16x8*)&Bs[(wn * 64 + nt * 16 + lan) * 32 + quad * 8];
#pragma unroll
    for (int mt = 0; mt < 4; ++mt)
#pragma unroll
      for (int nt = 0; nt < 4; ++nt)
        acc[mt][nt] = mfma16(af[mt], bfr[nt], acc[mt][nt]);
    __syncthreads();
  }
#pragma unroll
  for (int nt = 0; nt < 4; ++nt) {
    const int n = nBase + wn * 64 + nt * 16 + lan;
    const float bi = bo[n];
#pragma unroll
    for (int mt = 0; mt < 4; ++mt) {
      const int m0 = mBase + wm * 64 + mt * 16 + quad * 4;
      floatx4 v = acc[mt][nt];
#pragma unroll
      for (int r = 0; r < 4; ++r) {
        const size_t idx = (size_t)(m0 + r) * 1024 + n;
        y[idx] = f2bf(v[r] + bi + bf2f(xres[idx]));
      }
    }
  }
}

// ---------------------------------------------------------------------------
// LayerNorm: one block per row (D=1024), fp32 out
// ---------------------------------------------------------------------------
__global__ __launch_bounds__(256) void k_ln(
    const short* __restrict__ y, const float* __restrict__ g,
    const float* __restrict__ be, float* __restrict__ out) {
  const int row = blockIdx.x;
  const int t = threadIdx.x;
  const short* yr = y + (size_t)row * 1024;
  bf16x4 v4 = *(const bf16x4*)&yr[t * 4];
  float v0 = bf2f(v4.x), v1 = bf2f(v4.y), v2 = bf2f(v4.z), v3 = bf2f(v4.w);
  float s = v0 + v1 + v2 + v3;
  float s2 = v0 * v0 + v1 * v1 + v2 * v2 + v3 * v3;
#pragma unroll
  for (int off = 1; off < 64; off <<= 1) {
    s  += __shfl_xor(s, off);
    s2 += __shfl_xor(s2, off);
  }
  __shared__ float red[8];
  const int w = t >> 6;
  if ((t & 63) == 0) { red[w] = s; red[w + 4] = s2; }
  __syncthreads();
  s  = red[0] + red[1] + red[2] + red[3];
  s2 = red[4] + red[5] + red[6] + red[7];
  const float mu = s * (1.f / 1024.f);
  const float var = s2 * (1.f / 1024.f) - mu * mu;
  const float rstd = rsqrtf(var + 1e-5f);
  const int c = t * 4;
  float4 o;
  o.x = (v0 - mu) * rstd * g[c]     + be[c];
  o.y = (v1 - mu) * rstd * g[c + 1] + be[c + 1];
  o.z = (v2 - mu) * rstd * g[c + 2] + be[c + 2];
  o.w = (v3 - mu) * rstd * g[c + 3] + be[c + 3];
  *(float4*)&out[(size_t)row * 1024 + c] = o;
}

// ---------------------------------------------------------------------------
extern "C" void kernel_launch(void* const* d_in, const int* in_sizes, int n_in,
                              void* d_out, int out_size, void* d_ws,
                              size_t ws_size, hipStream_t stream) {
  const float* board    = (const float*)d_in[0];
  const float* emb_W    = (const float*)d_in[1];
  const float* emb_b    = (const float*)d_in[2];
  const float* pos      = (const float*)d_in[3];
  const float* Wq       = (const float*)d_in[4];
  const float* bq       = (const float*)d_in[5];
  const float* Wk       = (const float*)d_in[6];
  const float* bk       = (const float*)d_in[7];
  const float* Wv       = (const float*)d_in[8];
  const float* bv       = (const float*)d_in[9];
  const float* Wo       = (const float*)d_in[10];
  const float* bo       = (const float*)d_in[11];
  const float* rel_bias = (const float*)d_in[12];
  const float* ln_g     = (const float*)d_in[13];
  const float* ln_b     = (const float*)d_in[14];

  // workspace carve (bf16 buffers). Peak ~648 MB.
  char* ws = (char*)d_ws;
  short* Wqkv_t = (short*)ws; ws += (size_t)3072 * 1024 * 2;   //  6 MB (N,K)
  short* Wo_t   = (short*)ws; ws += (size_t)1024 * 1024 * 2;   //  2 MB (N,K)
  short* embWt  = (short*)ws; ws += (size_t)1024 * 128 * 2;    // .25 MB (N,Kpad)
  short* xb     = (short*)ws; ws += (size_t)65536 * 1024 * 2;  // 128 MB x bf16
  short* qb     = (short*)ws; ws += (size_t)16384 * 4096 * 2;  // 128 MB (b,h,s,dh)
  short* kb     = (short*)ws; ws += (size_t)16384 * 4096 * 2;  // 128 MB (b,h,s,dh)
  short* vtb    = (short*)ws; ws += (size_t)16384 * 4096 * 2;  // 128 MB (b,h,dh,s)
  short* ob     = (short*)ws; ws += (size_t)65536 * 1024 * 2;  // 128 MB (m,1024)
  short* yb     = kb;  // reuse: k no longer needed after attention

  dim3 tb(32, 8);
  k_transpose_bf16<<<dim3(32, 32), tb, 0, stream>>>(Wq, Wqkv_t);
  k_transpose_bf16<<<dim3(32, 32), tb, 0, stream>>>(Wk, Wqkv_t + (size_t)1024 * 1024);
  k_transpose_bf16<<<dim3(32, 32), tb, 0, stream>>>(Wv, Wqkv_t + (size_t)2 * 1024 * 1024);
  k_transpose_bf16<<<dim3(32, 32), tb, 0, stream>>>(Wo, Wo_t);
  k_embWt<<<512, 256, 0, stream>>>(emb_W, embWt);

  k_embed<<<8192, 256, 0, stream>>>(board, embWt, emb_b, pos, xb);
  k_gemm_qkv<<<12288, 256, 0, stream>>>(xb, Wqkv_t, bq, bk, bv, qb, kb, vtb);
  k_attn<<<4096, 256, 0, stream>>>(qb, kb, vtb, rel_bias, ob);
  k_gemm_oproj<<<4096, 256, 0, stream>>>(ob, Wo_t, bo, xb, yb);
  k_ln<<<65536, 256, 0, stream>>>(yb, ln_g, ln_b, (float*)d_out);
}

// Round 2
// 1344.536 us; speedup vs baseline: 1.0978x; 1.0978x over previous
//
#include <hip/hip_runtime.h>
#include <hip/hip_bf16.h>
#include <stdint.h>

// ---------------------------------------------------------------------------
// BoardEmbeddingWithTopology: embed GEMM -> QKV GEMM -> per-head attention
// with learned 64x64 relative bias -> O-proj GEMM + residual -> LayerNorm.
// All GEMMs: bf16 MFMA 16x16x32, 128x128 tile, BK=32, global_load_lds(16B),
// 4 waves x (4x4 16x16 frags). Weights pre-transposed to (N,K) bf16.
// R1: XCD-aware supertile swizzle (GROUP_M=8 mtiles resident in L2, ntile
// inner) on qkv/oproj/embed — kills the 15x A-refetch seen in rocprof
// (FETCH 2.17 GB vs 140 MB ideal on k_gemm_qkv).
// ---------------------------------------------------------------------------

typedef float  floatx4 __attribute__((ext_vector_type(4)));
typedef short  bf16x8  __attribute__((ext_vector_type(8)));
typedef short  bf16x4  __attribute__((ext_vector_type(4)));

__device__ __forceinline__ short f2bf(float f) {
  __hip_bfloat16 h = __float2bfloat16(f);
  return *reinterpret_cast<short*>(&h);
}
__device__ __forceinline__ float bf2f(short s) {
  union { float f; uint32_t u; } c;
  c.u = ((uint32_t)(uint16_t)s) << 16;
  return c.f;
}
__device__ __forceinline__ floatx4 mfma16(bf16x8 a, bf16x8 b, floatx4 c) {
  return __builtin_amdgcn_mfma_f32_16x16x32_bf16(a, b, c, 0, 0, 0);
}

// async global->LDS, 16B per lane; lds dst must be wave-uniform base.
#define ASYNC_CP16(gsrc, ldst)                                                 \
  __builtin_amdgcn_global_load_lds(                                            \
      (const __attribute__((address_space(1))) void*)(gsrc),                   \
      (__attribute__((address_space(3))) void*)(ldst), 16, 0, 0)

// ---------------------------------------------------------------------------
// Prep: transpose 1024x1024 f32 weight -> (N,K) bf16
// ---------------------------------------------------------------------------
__global__ void k_transpose_bf16(const float* __restrict__ src,
                                 short* __restrict__ dst) {
  __shared__ float tile[32][33];
  const int bx = blockIdx.x * 32, by = blockIdx.y * 32;
  const int tx = threadIdx.x, ty = threadIdx.y;
#pragma unroll
  for (int i = 0; i < 32; i += 8)
    tile[ty + i][tx] = src[(size_t)(by + ty + i) * 1024 + bx + tx];
  __syncthreads();
#pragma unroll
  for (int i = 0; i < 32; i += 8)
    dst[(size_t)(bx + ty + i) * 1024 + by + tx] = f2bf(tile[tx][ty + i]);
}

// embW (119,1024) f32 -> embW_t (1024,128) bf16, zero-padded K 119->128
__global__ void k_embWt(const float* __restrict__ embW, short* __restrict__ dst) {
  const int idx = blockIdx.x * 256 + threadIdx.x;  // 1024*128
  const int n = idx >> 7, c = idx & 127;
  dst[idx] = f2bf((c < 119) ? embW[(size_t)c * 1024 + n] : 0.f);
}

// ---------------------------------------------------------------------------
// Embed: x[b,s,n] = sum_c board[b,c,s]*embW[c,n] + emb_b[n] + pos[s,n] (bf16)
// one block per (board b, 128-col ntile); A = board[b]^T staged in LDS.
// ---------------------------------------------------------------------------
__global__ __launch_bounds__(256) void k_embed(
    const float* __restrict__ board, const short* __restrict__ embWt,
    const float* __restrict__ emb_b, const float* __restrict__ pos,
    short* __restrict__ x) {
  __shared__ short As[64 * 136];   // [s][c], +8 pad breaks write conflicts
  __shared__ short Bs[128 * 32];   // [n][k-chunk]
  const int t = threadIdx.x, l = t & 63, w = t >> 6;
  const int quad = l >> 4, lan = l & 15;
  // XCD-aware remap: the 8 ntile-blocks of one board land on one XCD.
  const int xcd = blockIdx.x & 7;
  const int lin = (blockIdx.x >> 3) + xcd * 1024;  // 8192/8
  const int b = lin >> 3, nBase = (lin & 7) << 7;
  const float* bb = board + (size_t)b * (119 * 64);
  const int s = t & 63;
#pragma unroll
  for (int it = 0; it < 16; ++it) {
    const int c0 = ((t >> 6) + it * 4) * 2;
    float u0 = (c0 < 119) ? bb[c0 * 64 + s] : 0.f;
    float u1 = (c0 + 1 < 119) ? bb[(c0 + 1) * 64 + s] : 0.f;
    short2 pr; pr.x = f2bf(u0); pr.y = f2bf(u1);
    *(short2*)&As[s * 136 + c0] = pr;
  }
  const short* Bg0 = embWt + (size_t)(nBase + (t >> 2)) * 128 + (t & 3) * 8;
  const short* Bg1 = Bg0 + (size_t)64 * 128;
  short* Bs0 = &Bs[(w * 16) * 32];
  short* Bs1 = &Bs[(64 + w * 16) * 32];
  floatx4 acc[4][2] = {};
  __syncthreads();
  for (int kk = 0; kk < 4; ++kk) {
    ASYNC_CP16(Bg0 + kk * 32, Bs0);
    ASYNC_CP16(Bg1 + kk * 32, Bs1);
    __syncthreads();
    bf16x8 af[4], bfr[2];
#pragma unroll
    for (int mt = 0; mt < 4; ++mt)
      af[mt] = *(const bf16x8*)&As[(mt * 16 + lan) * 136 + kk * 32 + quad * 8];
#pragma unroll
    for (int n2 = 0; n2 < 2; ++n2)
      bfr[n2] = *(const bf16x8*)&Bs[(w * 32 + n2 * 16 + lan) * 32 + quad * 8];
#pragma unroll
    for (int mt = 0; mt < 4; ++mt)
#pragma unroll
      for (int n2 = 0; n2 < 2; ++n2)
        acc[mt][n2] = mfma16(af[mt], bfr[n2], acc[mt][n2]);
    __syncthreads();
  }
#pragma unroll
  for (int n2 = 0; n2 < 2; ++n2) {
    const int n = nBase + w * 32 + n2 * 16 + lan;
    const float bi = emb_b[n];
#pragma unroll
    for (int mt = 0; mt < 4; ++mt) {
      const int s0 = mt * 16 + quad * 4;
      floatx4 v = acc[mt][n2];
#pragma unroll
      for (int r = 0; r < 4; ++r) {
        const int ss = s0 + r;
        x[((size_t)b * 64 + ss) * 1024 + n] = f2bf(v[r] + bi + pos[ss * 1024 + n]);
      }
    }
  }
}

// ---------------------------------------------------------------------------
// QKV GEMM: x(65536,1024)bf16 @ Wqkv_t(3072,1024)bf16 -> q,k (b,h,s,dh) and
// v transposed (b,h,dh,s), all bf16. m97 structure + supertile swizzle.
// ---------------------------------------------------------------------------
__global__ __launch_bounds__(256) void k_gemm_qkv(
    const short* __restrict__ A, const short* __restrict__ Bt,
    const float* __restrict__ bq, const float* __restrict__ bk,
    const float* __restrict__ bv, short* __restrict__ qb,
    short* __restrict__ kb, short* __restrict__ vtb) {
  __shared__ short As[128 * 32];
  __shared__ short Bs[128 * 32];
  const int t = threadIdx.x, l = t & 63, w = t >> 6;
  const int quad = l >> 4, lan = l & 15;
  // XCD-aware supertile decode: per-XCD contiguous lin; groups of 8 mtiles
  // (2 MB of A strips, L2-resident) iterate over all 24 ntiles.
  const int xcd = blockIdx.x & 7;
  const int lin = (blockIdx.x >> 3) + xcd * 1536;   // 12288/8
  const int grp = lin / 192;                        // 8 mtiles * 24 ntiles
  const int rem = lin - grp * 192;
  const int mBase = ((grp << 3) + (rem & 7)) << 7;
  const int nBase = (rem >> 3) << 7;
  const int wm = w >> 1, wn = w & 1;

  const short* Ag0 = A + (size_t)(mBase + (t >> 2)) * 1024 + (t & 3) * 8;
  const short* Ag1 = Ag0 + (size_t)64 * 1024;
  const short* Bg0 = Bt + (size_t)(nBase + (t >> 2)) * 1024 + (t & 3) * 8;
  const short* Bg1 = Bg0 + (size_t)64 * 1024;
  short* As0 = &As[(w * 16) * 32];
  short* As1 = &As[(64 + w * 16) * 32];
  short* Bs0 = &Bs[(w * 16) * 32];
  short* Bs1 = &Bs[(64 + w * 16) * 32];

  floatx4 acc[4][4] = {};
  for (int kk = 0; kk < 32; ++kk) {
    const int ko = kk * 32;
    ASYNC_CP16(Ag0 + ko, As0);
    ASYNC_CP16(Ag1 + ko, As1);
    ASYNC_CP16(Bg0 + ko, Bs0);
    ASYNC_CP16(Bg1 + ko, Bs1);
    __syncthreads();
    bf16x8 af[4], bfr[4];
#pragma unroll
    for (int mt = 0; mt < 4; ++mt)
      af[mt] = *(const bf16x8*)&As[(wm * 64 + mt * 16 + lan) * 32 + quad * 8];
#pragma unroll
    for (int nt = 0; nt < 4; ++nt)
      bfr[nt] = *(const bf16x8*)&Bs[(wn * 64 + nt * 16 + lan) * 32 + quad * 8];
#pragma unroll
    for (int mt = 0; mt < 4; ++mt)
#pragma unroll
      for (int nt = 0; nt < 4; ++nt)
        acc[mt][nt] = mfma16(af[mt], bfr[nt], acc[mt][nt]);
    __syncthreads();
  }
  // epilogue: block's 128 cols lie entirely in one of q/k/v (1024 % 128 == 0)
  const int region = nBase >> 10;
  const int nb = nBase & 1023;
  const float* bias = (region == 0) ? bq : (region == 1) ? bk : bv;
  short* qk = (region == 0) ? qb : kb;
#pragma unroll
  for (int nt = 0; nt < 4; ++nt) {
    const int nn = nb + wn * 64 + nt * 16 + lan;
    const int h = nn >> 6, dh = nn & 63;
    const float bi = bias[nn];
#pragma unroll
    for (int mt = 0; mt < 4; ++mt) {
      const int m0 = mBase + wm * 64 + mt * 16 + quad * 4;
      const int b = m0 >> 6, s0 = m0 & 63;
      floatx4 v = acc[mt][nt];
      if (region < 2) {
        short* dst = qk + (((size_t)b * 16 + h) * 64 + s0) * 64 + dh;
        dst[0]   = f2bf(v.x + bi);
        dst[64]  = f2bf(v.y + bi);
        dst[128] = f2bf(v.z + bi);
        dst[192] = f2bf(v.w + bi);
      } else {  // v stored transposed: vt[b,h,dh,s] -> contiguous in s
        bf16x4 pk = {f2bf(v.x + bi), f2bf(v.y + bi), f2bf(v.z + bi), f2bf(v.w + bi)};
        *(bf16x4*)(vtb + (((size_t)b * 16 + h) * 64 + dh) * 64 + s0) = pk;
      }
    }
  }
}

// ---------------------------------------------------------------------------
// Attention: one wave per (b,h). S = K @ Q^T so M=k-idx, N=q-idx: softmax
// over k is in-lane (16 regs) + shfl_xor(16,32). P -> LDS (bf16, padded
// rows) -> B-operand frags; o^T = V^T @ P via MFMA; /sum folded at store.
// ---------------------------------------------------------------------------
__global__ __launch_bounds__(256) void k_attn(
    const short* __restrict__ qb, const short* __restrict__ kb,
    const short* __restrict__ vtb, const float* __restrict__ rel_bias,
    short* __restrict__ ob) {
  __shared__ short P[4][64 * 72];  // per-wave, row stride 72 (16B-aligned, low conflict)
  const int t = threadIdx.x, l = t & 63, w = t >> 6;
  const int quad = l >> 4, lan = l & 15;
  const int b = blockIdx.x >> 2;
  const int h = (blockIdx.x & 3) * 4 + w;
  const short* q  = qb  + ((size_t)b * 16 + h) * 4096;
  const short* kp = kb  + ((size_t)b * 16 + h) * 4096;
  const short* vt = vtb + ((size_t)b * 16 + h) * 4096;
  const float* bias = rel_bias + (size_t)h * 4096;
  short* Pw = &P[w][0];

  bf16x8 kf[4][2], qf[4][2];
#pragma unroll
  for (int mt = 0; mt < 4; ++mt) {
    kf[mt][0] = *(const bf16x8*)&kp[(mt * 16 + lan) * 64 + quad * 8];
    kf[mt][1] = *(const bf16x8*)&kp[(mt * 16 + lan) * 64 + 32 + quad * 8];
  }
#pragma unroll
  for (int nt = 0; nt < 4; ++nt) {
    qf[nt][0] = *(const bf16x8*)&q[(nt * 16 + lan) * 64 + quad * 8];
    qf[nt][1] = *(const bf16x8*)&q[(nt * 16 + lan) * 64 + 32 + quad * 8];
  }
  floatx4 S[4][4];
#pragma unroll
  for (int mt = 0; mt < 4; ++mt)
#pragma unroll
    for (int nt = 0; nt < 4; ++nt) {
      floatx4 z = {0.f, 0.f, 0.f, 0.f};
      z = mfma16(kf[mt][0], qf[nt][0], z);
      S[mt][nt] = mfma16(kf[mt][1], qf[nt][1], z);
    }
  float rs[4];
#pragma unroll
  for (int nt = 0; nt < 4; ++nt) {
    const int qi = nt * 16 + lan;
    float sv[4][4];
    float m = -1e30f;
#pragma unroll
    for (int mt = 0; mt < 4; ++mt) {
      floatx4 bi = *(const floatx4*)&bias[qi * 64 + mt * 16 + quad * 4];
#pragma unroll
      for (int r = 0; r < 4; ++r) {
        sv[mt][r] = fmaf(S[mt][nt][r], 0.125f, bi[r]);
        m = fmaxf(m, sv[mt][r]);
      }
    }
    m = fmaxf(m, __shfl_xor(m, 16));
    m = fmaxf(m, __shfl_xor(m, 32));
    float sum = 0.f;
#pragma unroll
    for (int mt = 0; mt < 4; ++mt) {
      float p0 = exp2f((sv[mt][0] - m) * 1.4426950408889634f);
      float p1 = exp2f((sv[mt][1] - m) * 1.4426950408889634f);
      float p2 = exp2f((sv[mt][2] - m) * 1.4426950408889634f);
      float p3 = exp2f((sv[mt][3] - m) * 1.4426950408889634f);
      sum += p0 + p1 + p2 + p3;
      bf16x4 pk = {f2bf(p0), f2bf(p1), f2bf(p2), f2bf(p3)};
      *(bf16x4*)&Pw[qi * 72 + mt * 16 + quad * 4] = pk;
    }
    sum += __shfl_xor(sum, 16);
    sum += __shfl_xor(sum, 32);
    rs[nt] = 1.0f / sum;
  }
  bf16x8 pf[4][2];
#pragma unroll
  for (int nt = 0; nt < 4; ++nt) {
    pf[nt][0] = *(const bf16x8*)&Pw[(nt * 16 + lan) * 72 + quad * 8];
    pf[nt][1] = *(const bf16x8*)&Pw[(nt * 16 + lan) * 72 + 32 + quad * 8];
  }
#pragma unroll
  for (int mo = 0; mo < 4; ++mo) {
    bf16x8 vf0 = *(const bf16x8*)&vt[(mo * 16 + lan) * 64 + quad * 8];
    bf16x8 vf1 = *(const bf16x8*)&vt[(mo * 16 + lan) * 64 + 32 + quad * 8];
#pragma unroll
    for (int nt = 0; nt < 4; ++nt) {
      floatx4 z = {0.f, 0.f, 0.f, 0.f};
      z = mfma16(vf0, pf[nt][0], z);
      z = mfma16(vf1, pf[nt][1], z);
      const int qi = nt * 16 + lan;
      const int dh0 = mo * 16 + quad * 4;
      const float r = rs[nt];
      bf16x4 pk = {f2bf(z.x * r), f2bf(z.y * r), f2bf(z.z * r), f2bf(z.w * r)};
      *(bf16x4*)&ob[((size_t)b * 64 + qi) * 1024 + h * 64 + dh0] = pk;
    }
  }
}

// ---------------------------------------------------------------------------
// O-proj GEMM + residual: y = o @ Wo + bo + x (bf16 out)
// ---------------------------------------------------------------------------
__global__ __launch_bounds__(256) void k_gemm_oproj(
    const short* __restrict__ A, const short* __restrict__ Bt,
    const float* __restrict__ bo, const short* __restrict__ xres,
    short* __restrict__ y) {
  __shared__ short As[128 * 32];
  __shared__ short Bs[128 * 32];
  const int t = threadIdx.x, l = t & 63, w = t >> 6;
  const int quad = l >> 4, lan = l & 15;
  // XCD-aware supertile decode (8 mtiles x 8 ntiles per group; B=2MB fits L2)
  const int xcd = blockIdx.x & 7;
  const int lin = (blockIdx.x >> 3) + xcd * 512;    // 4096/8
  const int grp = lin >> 6;                         // 8 mtiles * 8 ntiles
  const int rem = lin & 63;
  const int mBase = ((grp << 3) + (rem & 7)) << 7;
  const int nBase = (rem >> 3) << 7;
  const int wm = w >> 1, wn = w & 1;

  const short* Ag0 = A + (size_t)(mBase + (t >> 2)) * 1024 + (t & 3) * 8;
  const short* Ag1 = Ag0 + (size_t)64 * 1024;
  const short* Bg0 = Bt + (size_t)(nBase + (t >> 2)) * 1024 + (t & 3) * 8;
  const short* Bg1 = Bg0 + (size_t)64 * 1024;
  short* As0 = &As[(w * 16) * 32];
  short* As1 = &As[(64 + w * 16) * 32];
  short* Bs0 = &Bs[(w * 16) * 32];
  short* Bs1 = &Bs[(64 + w * 16) * 32];

  floatx4 acc[4][4] = {};
  for (int kk = 0; kk < 32; ++kk) {
    const int ko = kk * 32;
    ASYNC_CP16(Ag0 + ko, As0);
    ASYNC_CP16(Ag1 + ko, As1);
    ASYNC_CP16(Bg0 + ko, Bs0);
    ASYNC_CP16(Bg1 + ko, Bs1);
    __syncthreads();
    bf16x8 af[4], bfr[4];
#pragma unroll
    for (int mt = 0; mt < 4; ++mt)
      af[mt] = *(const bf16x8*)&As[(wm * 64 + mt * 16 + lan) * 32 + quad * 8];
#pragma unroll
    for (int nt = 0; nt < 4; ++nt)
      bfr[nt] = *(const bf16x8*)&Bs[(wn * 64 + nt * 16 + lan) * 32 + quad * 8];
#pragma unroll
    for (int mt = 0; mt < 4; ++mt)
#pragma unroll
      for (int nt = 0; nt < 4; ++nt)
        acc[mt][nt] = mfma16(af[mt], bfr[nt], acc[mt][nt]);
    __syncthreads();
  }
#pragma unroll
  for (int nt = 0; nt < 4; ++nt) {
    const int n = nBase + wn * 64 + nt * 16 + lan;
    const float bi = bo[n];
#pragma unroll
    for (int mt = 0; mt < 4; ++mt) {
      const int m0 = mBase + wm * 64 + mt * 16 + quad * 4;
      floatx4 v = acc[mt][nt];
#pragma unroll
      for (int r = 0; r < 4; ++r) {
        const size_t idx = (size_t)(m0 + r) * 1024 + n;
        y[idx] = f2bf(v[r] + bi + bf2f(xres[idx]));
      }
    }
  }
}

// ---------------------------------------------------------------------------
// LayerNorm: one block per row (D=1024), fp32 out
// ---------------------------------------------------------------------------
__global__ __launch_bounds__(256) void k_ln(
    const short* __restrict__ y, const float* __restrict__ g,
    const float* __restrict__ be, float* __restrict__ out) {
  const int row = blockIdx.x;
  const int t = threadIdx.x;
  const short* yr = y + (size_t)row * 1024;
  bf16x4 v4 = *(const bf16x4*)&yr[t * 4];
  float v0 = bf2f(v4.x), v1 = bf2f(v4.y), v2 = bf2f(v4.z), v3 = bf2f(v4.w);
  float s = v0 + v1 + v2 + v3;
  float s2 = v0 * v0 + v1 * v1 + v2 * v2 + v3 * v3;
#pragma unroll
  for (int off = 1; off < 64; off <<= 1) {
    s  += __shfl_xor(s, off);
    s2 += __shfl_xor(s2, off);
  }
  __shared__ float red[8];
  const int w = t >> 6;
  if ((t & 63) == 0) { red[w] = s; red[w + 4] = s2; }
  __syncthreads();
  s  = red[0] + red[1] + red[2] + red[3];
  s2 = red[4] + red[5] + red[6] + red[7];
  const float mu = s * (1.f / 1024.f);
  const float var = s2 * (1.f / 1024.f) - mu * mu;
  const float rstd = rsqrtf(var + 1e-5f);
  const int c = t * 4;
  float4 o;
  o.x = (v0 - mu) * rstd * g[c]     + be[c];
  o.y = (v1 - mu) * rstd * g[c + 1] + be[c + 1];
  o.z = (v2 - mu) * rstd * g[c + 2] + be[c + 2];
  o.w = (v3 - mu) * rstd * g[c + 3] + be[c + 3];
  *(float4*)&out[(size_t)row * 1024 + c] = o;
}

// ---------------------------------------------------------------------------
extern "C" void kernel_launch(void* const* d_in, const int* in_sizes, int n_in,
                              void* d_out, int out_size, void* d_ws,
                              size_t ws_size, hipStream_t stream) {
  const float* board    = (const float*)d_in[0];
  const float* emb_W    = (const float*)d_in[1];
  const float* emb_b    = (const float*)d_in[2];
  const float* pos      = (const float*)d_in[3];
  const float* Wq       = (const float*)d_in[4];
  const float* bq       = (const float*)d_in[5];
  const float* Wk       = (const float*)d_in[6];
  const float* bk       = (const float*)d_in[7];
  const float* Wv       = (const float*)d_in[8];
  const float* bv       = (const float*)d_in[9];
  const float* Wo       = (const float*)d_in[10];
  const float* bo       = (const float*)d_in[11];
  const float* rel_bias = (const float*)d_in[12];
  const float* ln_g     = (const float*)d_in[13];
  const float* ln_b     = (const float*)d_in[14];

  // workspace carve (bf16 buffers). Peak ~648 MB.
  char* ws = (char*)d_ws;
  short* Wqkv_t = (short*)ws; ws += (size_t)3072 * 1024 * 2;   //  6 MB (N,K)
  short* Wo_t   = (short*)ws; ws += (size_t)1024 * 1024 * 2;   //  2 MB (N,K)
  short* embWt  = (short*)ws; ws += (size_t)1024 * 128 * 2;    // .25 MB (N,Kpad)
  short* xb     = (short*)ws; ws += (size_t)65536 * 1024 * 2;  // 128 MB x bf16
  short* qb     = (short*)ws; ws += (size_t)16384 * 4096 * 2;  // 128 MB (b,h,s,dh)
  short* kb     = (short*)ws; ws += (size_t)16384 * 4096 * 2;  // 128 MB (b,h,s,dh)
  short* vtb    = (short*)ws; ws += (size_t)16384 * 4096 * 2;  // 128 MB (b,h,dh,s)
  short* ob     = (short*)ws; ws += (size_t)65536 * 1024 * 2;  // 128 MB (m,1024)
  short* yb     = kb;  // reuse: k no longer needed after attention

  dim3 tb(32, 8);
  k_transpose_bf16<<<dim3(32, 32), tb, 0, stream>>>(Wq, Wqkv_t);
  k_transpose_bf16<<<dim3(32, 32), tb, 0, stream>>>(Wk, Wqkv_t + (size_t)1024 * 1024);
  k_transpose_bf16<<<dim3(32, 32), tb, 0, stream>>>(Wv, Wqkv_t + (size_t)2 * 1024 * 1024);
  k_transpose_bf16<<<dim3(32, 32), tb, 0, stream>>>(Wo, Wo_t);
  k_embWt<<<512, 256, 0, stream>>>(emb_W, embWt);

  k_embed<<<8192, 256, 0, stream>>>(board, embWt, emb_b, pos, xb);
  k_gemm_qkv<<<12288, 256, 0, stream>>>(xb, Wqkv_t, bq, bk, bv, qb, kb, vtb);
  k_attn<<<4096, 256, 0, stream>>>(qb, kb, vtb, rel_bias, ob);
  k_gemm_oproj<<<4096, 256, 0, stream>>>(ob, Wo_t, bo, xb, yb);
  k_ln<<<65536, 256, 0, stream>>>(yb, ln_g, ln_b, (float*)d_out);
}